// Round 9
// baseline (264.831 us; speedup 1.0000x reference)
//
#include <hip/hip_runtime.h>

typedef __bf16    bf16x8 __attribute__((ext_vector_type(8)));
typedef _Float16  f16x8  __attribute__((ext_vector_type(8)));
typedef _Float16  f16x4  __attribute__((ext_vector_type(4)));
typedef float     f32x4  __attribute__((ext_vector_type(4)));

#define MFMA16(a,b,c)  __builtin_amdgcn_mfma_f32_16x16x32_bf16((a),(b),(c),0,0,0)
#define MFMAF16(a,b,c) __builtin_amdgcn_mfma_f32_16x16x32_f16((a),(b),(c),0,0,0)

#define AS1(p) (const __attribute__((address_space(1))) void*)(p)
#define AS3(p) (__attribute__((address_space(3))) void*)(p)
#define GLL16(g, l) __builtin_amdgcn_global_load_lds(AS1(g), AS3(l), 16, 0, 0)

#define VMCNT4 asm volatile("s_waitcnt vmcnt(4)" ::: "memory")
#define VMCNT0 asm volatile("s_waitcnt vmcnt(0)" ::: "memory")
#define RBAR   do { __builtin_amdgcn_s_barrier(); asm volatile("" ::: "memory"); } while (0)

__device__ __forceinline__ float fexp2(float x) {
  float r; asm("v_exp_f32 %0, %1" : "=v"(r) : "v"(x)); return r;
}

// B=4, N=2048, H=12, hd=64, D=768, M=B*N=8192
// Q stored pre-scaled by log2(e)/8 so softmax uses exp2 directly.
#define QSCALE 0.18033688011112042f

// ---------------- x -> (xh, xl) split bf16 ----------------
__global__ __launch_bounds__(256) void k_conv_x(const float* __restrict__ x,
                                                __bf16* __restrict__ xh,
                                                __bf16* __restrict__ xl) {
  int i = blockIdx.x * 256 + threadIdx.x;
  const float4* p = (const float4*)x + (size_t)i * 2;
  float4 a = p[0], b = p[1];
  float v[8] = {a.x, a.y, a.z, a.w, b.x, b.y, b.z, b.w};
  bf16x8 h, l;
#pragma unroll
  for (int j = 0; j < 8; ++j) {
    __bf16 hh = (__bf16)v[j];
    h[j] = hh;
    l[j] = (__bf16)(v[j] - (float)hh);
  }
  *(bf16x8*)(xh + (size_t)i * 8) = h;
  *(bf16x8*)(xl + (size_t)i * 8) = l;
}

// ------- weights: W[k][c] -> Wt[c][k] bf16 (hi/lo), out_proj -> f16 -------
__global__ __launch_bounds__(256) void k_conv_w(const float* __restrict__ wq,
                                                const float* __restrict__ wk,
                                                const float* __restrict__ wv,
                                                const float* __restrict__ op,
                                                __bf16* __restrict__ wt_h,
                                                __bf16* __restrict__ wt_l,
                                                _Float16* __restrict__ wot) {
  __shared__ float tile[32][33];
  int bid = blockIdx.x;
  int m = bid / 576, rem = bid % 576;
  int tr = rem / 24, tc = rem % 24;
  const float* src = (m == 0) ? wq : (m == 1) ? wk : (m == 2) ? wv : op;
  int tx = threadIdx.x & 31, ty = threadIdx.x >> 5;
  int r0 = tr * 32, c0 = tc * 32;
#pragma unroll
  for (int j = 0; j < 4; ++j)
    tile[ty + j * 8][tx] = src[(size_t)(r0 + ty + j * 8) * 768 + c0 + tx];
  __syncthreads();
#pragma unroll
  for (int j = 0; j < 4; ++j) {
    float v = tile[tx][ty + j * 8];
    size_t o = (size_t)(c0 + ty + j * 8) * 768 + r0 + tx;
    if (m < 3) {
      size_t oo = (size_t)m * (768 * 768) + o;
      __bf16 h = (__bf16)v;
      wt_h[oo] = h;
      wt_l[oo] = (__bf16)(v - (float)h);
    } else {
      wot[o] = (_Float16)v;
    }
  }
}

// ------- QK GEMM: 3-term split-bf16, counted-vmcnt staggered staging -------
// hi tensors triple-buffered, lo double-buffered; raw barriers, vmcnt(4).
__global__ __launch_bounds__(256) void k_qk_gemm(
    const __bf16* __restrict__ Ah, const __bf16* __restrict__ Al,
    const __bf16* __restrict__ Bh, const __bf16* __restrict__ Bl,
    _Float16* __restrict__ qf_o, _Float16* __restrict__ kf_o) {
  __shared__ __align__(16) __bf16 AsH[3][128 * 32];
  __shared__ __align__(16) __bf16 BsH[3][128 * 32];
  __shared__ __align__(16) __bf16 AsL[2][128 * 32];
  __shared__ __align__(16) __bf16 BsL[2][128 * 32];
  int t = threadIdx.x, lane = t & 63, wid = t >> 6;
  int l15 = lane & 15, lh = lane >> 4;
  int bid = blockIdx.x;
  int mt = bid & 63, nt = bid >> 6;          // 64 x 12
  int m0 = mt * 128, n0 = nt * 128;
  int wr = wid >> 1, wc = wid & 1;
  f32x4 acc[4][4];
#pragma unroll
  for (int i = 0; i < 4; ++i)
#pragma unroll
    for (int j = 0; j < 4; ++j) acc[i][j] = (f32x4){0.f, 0.f, 0.f, 0.f};

  // staging: inverse-swizzled global source, linear LDS dest (rule #21)
  int row0 = t >> 2;
  int kkA = (((t & 3) ^ ((row0 >> 1) & 3)) << 3);
  const __bf16* gAh = Ah + (size_t)(m0 + row0) * 768 + kkA;
  const __bf16* gAl = Al + (size_t)(m0 + row0) * 768 + kkA;
  const __bf16* gBh = Bh + (size_t)(n0 + row0) * 768 + kkA;
  const __bf16* gBl = Bl + (size_t)(n0 + row0) * 768 + kkA;
  const size_t RSK = (size_t)64 * 768;       // 64-row stride

#define STG_HI(b, k0s) do {                                                  \
    char* dA = (char*)AsH[b] + wid * 1024;                                   \
    char* dB = (char*)BsH[b] + wid * 1024;                                   \
    GLL16(gAh + (k0s), dA); GLL16(gAh + (k0s) + RSK, dA + 4096);             \
    GLL16(gBh + (k0s), dB); GLL16(gBh + (k0s) + RSK, dB + 4096);             \
  } while (0)
#define STG_LO(b, k0s) do {                                                  \
    char* dA = (char*)AsL[b] + wid * 1024;                                   \
    char* dB = (char*)BsL[b] + wid * 1024;                                   \
    GLL16(gAl + (k0s), dA); GLL16(gAl + (k0s) + RSK, dA + 4096);             \
    GLL16(gBl + (k0s), dB); GLL16(gBl + (k0s) + RSK, dB + 4096);             \
  } while (0)

  // prologue: hi(0)->b0, lo(0)->b0, hi(32)->b1 ; wait oldest 8 of 12
  STG_HI(0, 0);
  STG_LO(0, 0);
  STG_HI(1, 32);
  VMCNT4;
  RBAR;

  int cur3 = 0, curl = 0;
  for (int tt = 0; tt < 24; ++tt) {
    if (tt < 23) STG_LO(curl ^ 1, (tt + 1) * 32);
    int tg3 = cur3 + 2; if (tg3 >= 3) tg3 -= 3;    // buffer released last iter
    if (tt < 22) STG_HI(tg3, (tt + 2) * 32);

    bf16x8 af[4], alf[4], bf_[4], blf[4];
#pragma unroll
    for (int i = 0; i < 4; ++i) {
      int rowA = wr * 64 + i * 16 + l15;
      int aoff = rowA * 64 + (((lh ^ (rowA >> 1)) & 3) << 4);
      int rowB = wc * 64 + i * 16 + l15;
      int boff = rowB * 64 + (((lh ^ (rowB >> 1)) & 3) << 4);
      af[i]  = *(const bf16x8*)((char*)AsH[cur3] + aoff);
      alf[i] = *(const bf16x8*)((char*)AsL[curl] + aoff);
      bf_[i] = *(const bf16x8*)((char*)BsH[cur3] + boff);
      blf[i] = *(const bf16x8*)((char*)BsL[curl] + boff);
    }
    __builtin_amdgcn_s_setprio(1);
#pragma unroll
    for (int i = 0; i < 4; ++i)
#pragma unroll
      for (int j = 0; j < 4; ++j) {
        acc[i][j] = MFMA16(af[i], bf_[j], acc[i][j]);
        acc[i][j] = MFMA16(af[i], blf[j], acc[i][j]);
        acc[i][j] = MFMA16(alf[i], bf_[j], acc[i][j]);
      }
    __builtin_amdgcn_s_setprio(0);

    if (tt < 22) { VMCNT4; } else { VMCNT0; }
    RBAR;
    cur3 = cur3 + 1 == 3 ? 0 : cur3 + 1;
    curl ^= 1;
  }
#undef STG_HI
#undef STG_LO

#pragma unroll
  for (int j = 0; j < 4; ++j) {
    int c = n0 + wc * 64 + j * 16 + l15;
    int which = c / 768; int cc = c - which * 768;
    int hh = cc >> 6, d = cc & 63;
#pragma unroll
    for (int i = 0; i < 4; ++i)
#pragma unroll
      for (int r = 0; r < 4; ++r) {
        int m = m0 + wr * 64 + i * 16 + lh * 4 + r;
        int bb = m >> 11, n = m & 2047;
        float v = acc[i][j][r];
        size_t o = ((size_t)(bb * 12 + hh) * 2048 + n) * 64 + d;
        if (which == 0) qf_o[o] = (_Float16)(v * QSCALE);
        else            kf_o[o] = (_Float16)v;
      }
  }
}

// ------- V GEMM: 1-term bf16, triple-buffer counted-vmcnt -------
__global__ __launch_bounds__(256) void k_v_gemm(
    const __bf16* __restrict__ A, const __bf16* __restrict__ Bt,
    _Float16* __restrict__ vT_o) {
  __shared__ __align__(16) __bf16 As[3][128 * 32];
  __shared__ __align__(16) __bf16 Bs[3][128 * 32];
  int t = threadIdx.x, lane = t & 63, wid = t >> 6;
  int l15 = lane & 15, lh = lane >> 4;
  int bid = blockIdx.x;
  int mt = bid & 63, nt = bid >> 6;          // 64 x 6
  int m0 = mt * 128, n0 = 1536 + nt * 128;
  int wr = wid >> 1, wc = wid & 1;
  f32x4 acc[4][4];
#pragma unroll
  for (int i = 0; i < 4; ++i)
#pragma unroll
    for (int j = 0; j < 4; ++j) acc[i][j] = (f32x4){0.f, 0.f, 0.f, 0.f};
  int row0 = t >> 2;
  int kkA = (((t & 3) ^ ((row0 >> 1) & 3)) << 3);
  const __bf16* gA = A + (size_t)(m0 + row0) * 768 + kkA;
  const __bf16* gB = Bt + (size_t)(n0 + row0) * 768 + kkA;
  const size_t RSK = (size_t)64 * 768;

#define STG(b, k0s) do {                                                     \
    char* dA = (char*)As[b] + wid * 1024;                                    \
    char* dB = (char*)Bs[b] + wid * 1024;                                    \
    GLL16(gA + (k0s), dA); GLL16(gA + (k0s) + RSK, dA + 4096);               \
    GLL16(gB + (k0s), dB); GLL16(gB + (k0s) + RSK, dB + 4096);               \
  } while (0)

  STG(0, 0);
  STG(1, 32);
  VMCNT4;
  RBAR;

  int cur3 = 0;
  for (int tt = 0; tt < 24; ++tt) {
    int tg3 = cur3 + 2; if (tg3 >= 3) tg3 -= 3;
    if (tt < 22) STG(tg3, (tt + 2) * 32);
    bf16x8 af[4], bf_[4];
#pragma unroll
    for (int i = 0; i < 4; ++i) {
      int rowA = wr * 64 + i * 16 + l15;
      int aoff = rowA * 64 + (((lh ^ (rowA >> 1)) & 3) << 4);
      int rowB = wc * 64 + i * 16 + l15;
      int boff = rowB * 64 + (((lh ^ (rowB >> 1)) & 3) << 4);
      af[i]  = *(const bf16x8*)((char*)As[cur3] + aoff);
      bf_[i] = *(const bf16x8*)((char*)Bs[cur3] + boff);
    }
    __builtin_amdgcn_s_setprio(1);
#pragma unroll
    for (int i = 0; i < 4; ++i)
#pragma unroll
      for (int j = 0; j < 4; ++j) acc[i][j] = MFMA16(af[i], bf_[j], acc[i][j]);
    __builtin_amdgcn_s_setprio(0);
    if (tt < 22) { VMCNT4; } else { VMCNT0; }
    RBAR;
    cur3 = cur3 + 1 == 3 ? 0 : cur3 + 1;
  }
#undef STG

#pragma unroll
  for (int j = 0; j < 4; ++j) {
    int c = n0 + wc * 64 + j * 16 + l15;
    int cc = c - 1536;
    int hh = cc >> 6, d = cc & 63;
#pragma unroll
    for (int i = 0; i < 4; ++i)
#pragma unroll
      for (int r = 0; r < 4; ++r) {
        int m = m0 + wr * 64 + i * 16 + lh * 4 + r;
        int bb = m >> 11, n = m & 2047;
        vT_o[((size_t)(bb * 12 + hh) * 64 + d) * 2048 + n] = (_Float16)acc[i][j][r];
      }
  }
}

// ---------------- causal flash attention (f16, dbuf, defer-max) ----------------
__global__ __launch_bounds__(256) void k_attn(
    const _Float16* __restrict__ Qf, const _Float16* __restrict__ Kf,
    const _Float16* __restrict__ Vt, _Float16* __restrict__ ctx) {
  __shared__ __align__(16) _Float16 Ks[2][64 * 64];
  __shared__ __align__(16) _Float16 Vs[2][64 * 64];
  __shared__ __align__(16) _Float16 Pt[4][32 * 64];
  int t = threadIdx.x, lane = t & 63, wid = t >> 6;
  int l15 = lane & 15, lh = lane >> 4;
  int bid = blockIdx.x;
  int bh = bid % 48;
  int qt = 15 - bid / 48;                    // heavy tiles dispatch first
  int qbase = qt * 128 + wid * 32;
  size_t base = (size_t)bh * (2048 * 64);
  char* ptw = (char*)Pt[wid];

  int skey = t >> 3, sdb = t & 7;
  int ssw = (sdb ^ (skey & 7)) * 8;
  const _Float16* ksrc = Kf + base + (size_t)skey * 64 + ssw;
  const _Float16* vsrc = Vt + base + (size_t)skey * 2048 + ssw;
  char* dK[2] = {(char*)Ks[0] + wid * 1024, (char*)Ks[1] + wid * 1024};
  char* dV[2] = {(char*)Vs[0] + wid * 1024, (char*)Vs[1] + wid * 1024};

#define ATT_STAGE(bb, k0s) do {                                    \
    GLL16(ksrc + (size_t)(k0s) * 64, dK[bb]);                      \
    GLL16(ksrc + (size_t)(k0s) * 64 + 2048, dK[bb] + 4096);        \
    GLL16(vsrc + (k0s), dV[bb]);                                   \
    GLL16(vsrc + (k0s) + 32 * 2048, dV[bb] + 4096);                \
  } while (0)

  f16x8 qf[2][2];
#pragma unroll
  for (int i = 0; i < 2; ++i)
#pragma unroll
    for (int kk = 0; kk < 2; ++kk)
      qf[i][kk] = *(const f16x8*)(Qf + base +
          (size_t)(qbase + i * 16 + l15) * 64 + kk * 32 + lh * 8);

  f32x4 o[2][4];
#pragma unroll
  for (int i = 0; i < 2; ++i)
#pragma unroll
    for (int d = 0; d < 4; ++d) o[i][d] = (f32x4){0.f, 0.f, 0.f, 0.f};
  float mrun[2] = {-1e30f, -1e30f}, lrun[2] = {0.f, 0.f};

  int nIter = 2 * qt + 2;
  ATT_STAGE(0, 0);
  asm volatile("s_waitcnt vmcnt(0)" ::: "memory");
  __syncthreads();

  for (int it = 0; it < nIter; ++it) {
    int cur = it & 1;
    int k0 = it * 64;
    if (it + 1 < nIter) ATT_STAGE(cur ^ 1, k0 + 64);

    if (k0 <= qbase + 31) {
      f32x4 s[4][2];
#pragma unroll
      for (int j = 0; j < 4; ++j)
#pragma unroll
        for (int i = 0; i < 2; ++i) s[j][i] = (f32x4){0.f, 0.f, 0.f, 0.f};
      __builtin_amdgcn_s_setprio(1);
#pragma unroll
      for (int j = 0; j < 4; ++j) {
        int kr = j * 16 + l15;
#pragma unroll
        for (int kk = 0; kk < 2; ++kk) {
          int sw = ((kk * 4 + lh) ^ (kr & 7)) << 4;
          f16x8 kf = *(const f16x8*)((char*)Ks[cur] + kr * 128 + sw);
          s[j][0] = MFMAF16(kf, qf[0][kk], s[j][0]);
          s[j][1] = MFMAF16(kf, qf[1][kk], s[j][1]);
        }
      }
      __builtin_amdgcn_s_setprio(0);

      if (k0 + 63 > qbase) {                 // diagonal: causal mask
#pragma unroll
        for (int j = 0; j < 4; ++j)
#pragma unroll
          for (int i = 0; i < 2; ++i)
#pragma unroll
            for (int r = 0; r < 4; ++r) {
              int key = k0 + j * 16 + lh * 4 + r;
              int qg = qbase + i * 16 + l15;
              if (key > qg) s[j][i][r] = -1e30f;
            }
      }

      // --- online softmax with defer-max (T13, THR=8 exp2-units) ---
#pragma unroll
      for (int i = 0; i < 2; ++i) {
        float m01 = fmaxf(fmaxf(s[0][i][0], s[0][i][1]), fmaxf(s[0][i][2], s[0][i][3]));
        float m23 = fmaxf(fmaxf(s[1][i][0], s[1][i][1]), fmaxf(s[1][i][2], s[1][i][3]));
        float m45 = fmaxf(fmaxf(s[2][i][0], s[2][i][1]), fmaxf(s[2][i][2], s[2][i][3]));
        float m67 = fmaxf(fmaxf(s[3][i][0], s[3][i][1]), fmaxf(s[3][i][2], s[3][i][3]));
        float mx = fmaxf(fmaxf(m01, m23), fmaxf(m45, m67));
        mx = fmaxf(mx, __shfl_xor(mx, 16));
        mx = fmaxf(mx, __shfl_xor(mx, 32));
        bool keep = !__all(mx <= mrun[i] + 8.f);
        float mn = mrun[i];
        if (keep) {
          mn = fmaxf(mrun[i], mx);
          float alpha = fexp2(mrun[i] - mn);
          mrun[i] = mn;
          lrun[i] *= alpha;
#pragma unroll
          for (int d = 0; d < 4; ++d) o[i][d] *= alpha;
        }
        float rsum = 0.f;
#pragma unroll
        for (int j = 0; j < 4; ++j)
#pragma unroll
          for (int r = 0; r < 4; ++r) {
            float e = fexp2(s[j][i][r] - mn);
            s[j][i][r] = e;
            rsum += e;
          }
        rsum += __shfl_xor(rsum, 16);
        rsum += __shfl_xor(rsum, 32);
        lrun[i] += rsum;
#pragma unroll
        for (int j = 0; j < 4; ++j) {
          f16x4 pk = { (_Float16)s[j][i][0], (_Float16)s[j][i][1],
                       (_Float16)s[j][i][2], (_Float16)s[j][i][3] };
          int row = 16 * i + l15;
          int boff = (row * 128 + j * 32 + lh * 8) ^ ((l15 & 7) << 4);
          *(f16x4*)(ptw + boff) = pk;
        }
      }
      asm volatile("" ::: "memory");
      f16x8 pa[2][2];
#pragma unroll
      for (int i = 0; i < 2; ++i)
#pragma unroll
        for (int kk = 0; kk < 2; ++kk) {
          int row = 16 * i + l15;
          int boff = (row * 128 + kk * 64 + lh * 16) ^ ((l15 & 7) << 4);
          pa[i][kk] = *(const f16x8*)(ptw + boff);
        }
      asm volatile("" ::: "memory");

      __builtin_amdgcn_s_setprio(1);
#pragma unroll
      for (int dt = 0; dt < 4; ++dt) {
        int dr = dt * 16 + l15;
#pragma unroll
        for (int kk = 0; kk < 2; ++kk) {
          int sw = ((kk * 4 + lh) ^ (dr & 7)) << 4;
          f16x8 vf = *(const f16x8*)((char*)Vs[cur] + dr * 128 + sw);
          o[0][dt] = MFMAF16(vf, pa[0][kk], o[0][dt]);
          o[1][dt] = MFMAF16(vf, pa[1][kk], o[1][dt]);
        }
      }
      __builtin_amdgcn_s_setprio(0);
    }
    asm volatile("s_waitcnt vmcnt(0)" ::: "memory");
    __syncthreads();
  }
#undef ATT_STAGE

  int b = bh / 12, hh = bh - (bh / 12) * 12;
  float inv[2] = {1.f / lrun[0], 1.f / lrun[1]};
#pragma unroll
  for (int i = 0; i < 2; ++i)
#pragma unroll
    for (int dt = 0; dt < 4; ++dt) {
      f16x4 cw = { (_Float16)(o[i][dt][0] * inv[i]), (_Float16)(o[i][dt][1] * inv[i]),
                   (_Float16)(o[i][dt][2] * inv[i]), (_Float16)(o[i][dt][3] * inv[i]) };
      int row = 16 * i + l15;
      int boff = (row * 128 + dt * 32 + lh * 8) ^ ((l15 & 7) << 4);
      *(f16x4*)(ptw + boff) = cw;
    }
  asm volatile("" ::: "memory");
  int lr = lane >> 1, hc = lane & 1;
#pragma unroll
  for (int q16 = 0; q16 < 4; ++q16) {
    int boff = (lr * 128 + hc * 64 + q16 * 16) ^ ((lr & 7) << 4);
    f16x8 vv = *(const f16x8*)(ptw + boff);
    *(f16x8*)(ctx + ((size_t)b * 2048 + qbase + lr) * 768 + hh * 64 + hc * 32 + q16 * 8) = vv;
  }
}

// ------- out projection: f16 in, fp32 out, triple-buffer counted-vmcnt -------
__global__ __launch_bounds__(256) void k_out_gemm(const _Float16* __restrict__ A,
                                                  const _Float16* __restrict__ Bt,
                                                  float* __restrict__ C) {
  __shared__ __align__(16) _Float16 As[3][128 * 32];
  __shared__ __align__(16) _Float16 Bs[3][128 * 32];
  int t = threadIdx.x, lane = t & 63, wid = t >> 6;
  int l15 = lane & 15, lh = lane >> 4;
  int bid = blockIdx.x;
  int mt = bid & 63, nt = bid >> 6;
  int m0 = mt * 128, n0 = nt * 128;
  int wr = wid >> 1, wc = wid & 1;
  f32x4 acc[4][4];
#pragma unroll
  for (int i = 0; i < 4; ++i)
#pragma unroll
    for (int j = 0; j < 4; ++j) acc[i][j] = (f32x4){0.f, 0.f, 0.f, 0.f};
  int row0 = t >> 2;
  int kkA = (((t & 3) ^ ((row0 >> 1) & 3)) << 3);
  const _Float16* gA = A + (size_t)(m0 + row0) * 768 + kkA;
  const _Float16* gB = Bt + (size_t)(n0 + row0) * 768 + kkA;
  const size_t RSK = (size_t)64 * 768;

#define STG(b, k0s) do {                                                     \
    char* dA = (char*)As[b] + wid * 1024;                                    \
    char* dB = (char*)Bs[b] + wid * 1024;                                    \
    GLL16(gA + (k0s), dA); GLL16(gA + (k0s) + RSK, dA + 4096);               \
    GLL16(gB + (k0s), dB); GLL16(gB + (k0s) + RSK, dB + 4096);               \
  } while (0)

  STG(0, 0);
  STG(1, 32);
  VMCNT4;
  RBAR;

  int cur3 = 0;
  for (int tt = 0; tt < 24; ++tt) {
    int tg3 = cur3 + 2; if (tg3 >= 3) tg3 -= 3;
    if (tt < 22) STG(tg3, (tt + 2) * 32);
    f16x8 af[4], bf_[4];
#pragma unroll
    for (int i = 0; i < 4; ++i) {
      int rowA = wr * 64 + i * 16 + l15;
      int aoff = rowA * 64 + (((lh ^ (rowA >> 1)) & 3) << 4);
      int rowB = wc * 64 + i * 16 + l15;
      int boff = rowB * 64 + (((lh ^ (rowB >> 1)) & 3) << 4);
      af[i]  = *(const f16x8*)((char*)As[cur3] + aoff);
      bf_[i] = *(const f16x8*)((char*)Bs[cur3] + boff);
    }
    __builtin_amdgcn_s_setprio(1);
#pragma unroll
    for (int i = 0; i < 4; ++i)
#pragma unroll
      for (int j = 0; j < 4; ++j) acc[i][j] = MFMAF16(af[i], bf_[j], acc[i][j]);
    __builtin_amdgcn_s_setprio(0);
    if (tt < 22) { VMCNT4; } else { VMCNT0; }
    RBAR;
    cur3 = cur3 + 1 == 3 ? 0 : cur3 + 1;
  }
#undef STG

#pragma unroll
  for (int j = 0; j < 4; ++j) {
    int c = n0 + wc * 64 + j * 16 + l15;
#pragma unroll
    for (int i = 0; i < 4; ++i)
#pragma unroll
      for (int r = 0; r < 4; ++r) {
        int m = m0 + wr * 64 + i * 16 + lh * 4 + r;
        C[(size_t)m * 768 + c] = acc[i][j][r];
      }
  }
}

extern "C" void kernel_launch(void* const* d_in, const int* in_sizes, int n_in,
                              void* d_out, int out_size, void* d_ws, size_t ws_size,
                              hipStream_t stream) {
  const float* x  = (const float*)d_in[0];
  const float* wq = (const float*)d_in[1];
  const float* wk = (const float*)d_in[2];
  const float* wv = (const float*)d_in[3];
  const float* op = (const float*)d_in[4];
  float* out = (float*)d_out;

  char* ws = (char*)d_ws;
  const size_t SZ = (size_t)8192 * 768 * 2;
  __bf16* xh     = (__bf16*)ws;    ws += SZ;
  __bf16* xl     = (__bf16*)ws;    ws += SZ;
  __bf16* wt_h   = (__bf16*)ws;    ws += (size_t)2304 * 768 * 2;
  __bf16* wt_l   = (__bf16*)ws;    ws += (size_t)2304 * 768 * 2;
  _Float16* wot  = (_Float16*)ws;  ws += (size_t)768 * 768 * 2;
  _Float16* qf   = (_Float16*)ws;  ws += SZ;
  _Float16* kf   = (_Float16*)ws;  ws += SZ;
  _Float16* vT   = (_Float16*)ws;  ws += SZ;
  _Float16* ctx  = (_Float16*)ws;  ws += SZ;

  hipLaunchKernelGGL(k_conv_x, dim3(3072), dim3(256), 0, stream, x, xh, xl);
  hipLaunchKernelGGL(k_conv_w, dim3(2304), dim3(256), 0, stream,
                     wq, wk, wv, op, wt_h, wt_l, wot);
  hipLaunchKernelGGL(k_qk_gemm, dim3(64 * 12), dim3(256), 0, stream,
                     xh, xl, wt_h, wt_l, qf, kf);
  hipLaunchKernelGGL(k_v_gemm, dim3(64 * 6), dim3(256), 0, stream, xh, wt_h, vT);
  hipLaunchKernelGGL(k_attn, dim3(48 * 16), dim3(256), 0, stream, qf, kf, vT, ctx);
  hipLaunchKernelGGL(k_out_gemm, dim3(64 * 6), dim3(256), 0, stream, ctx, wot, out);
}

// Round 11
// 246.660 us; speedup vs baseline: 1.0737x; 1.0737x over previous
//
#include <hip/hip_runtime.h>

typedef __bf16    bf16x8 __attribute__((ext_vector_type(8)));
typedef _Float16  f16x8  __attribute__((ext_vector_type(8)));
typedef _Float16  f16x4  __attribute__((ext_vector_type(4)));
typedef float     f32x4  __attribute__((ext_vector_type(4)));

#define MFMA16(a,b,c)  __builtin_amdgcn_mfma_f32_16x16x32_bf16((a),(b),(c),0,0,0)
#define MFMAF16(a,b,c) __builtin_amdgcn_mfma_f32_16x16x32_f16((a),(b),(c),0,0,0)

#define AS1(p) (const __attribute__((address_space(1))) void*)(p)
#define AS3(p) (__attribute__((address_space(3))) void*)(p)
#define GLL16(g, l) __builtin_amdgcn_global_load_lds(AS1(g), AS3(l), 16, 0, 0)

__device__ __forceinline__ float fexp2(float x) {
  float r; asm("v_exp_f32 %0, %1" : "=v"(r) : "v"(x)); return r;
}

// B=4, N=2048, H=12, hd=64, D=768, M=B*N=8192
// Q stored pre-scaled by log2(e)/8 so softmax uses exp2 directly.
#define QSCALE 0.18033688011112042f

// -------- merged conversions: x -> (xh,xl) split bf16 ; W -> Wt (hi/lo), Wot --------
// grid: 3072 conv_x blocks + 2304 conv_w blocks
__global__ __launch_bounds__(256) void k_conv(const float* __restrict__ x,
                                              const float* __restrict__ wq,
                                              const float* __restrict__ wk,
                                              const float* __restrict__ wv,
                                              const float* __restrict__ op,
                                              __bf16* __restrict__ xh,
                                              __bf16* __restrict__ xl,
                                              __bf16* __restrict__ wt_h,
                                              __bf16* __restrict__ wt_l,
                                              _Float16* __restrict__ wot) {
  __shared__ float tile[32][33];
  int bid = blockIdx.x;
  if (bid < 3072) {
    int i = bid * 256 + threadIdx.x;
    const float4* p = (const float4*)x + (size_t)i * 2;
    float4 a = p[0], b = p[1];
    float v[8] = {a.x, a.y, a.z, a.w, b.x, b.y, b.z, b.w};
    bf16x8 h, l;
#pragma unroll
    for (int j = 0; j < 8; ++j) {
      __bf16 hh = (__bf16)v[j];
      h[j] = hh;
      l[j] = (__bf16)(v[j] - (float)hh);
    }
    *(bf16x8*)(xh + (size_t)i * 8) = h;
    *(bf16x8*)(xl + (size_t)i * 8) = l;
    return;
  }
  int wb = bid - 3072;
  int m = wb / 576, rem = wb % 576;
  int tr = rem / 24, tc = rem % 24;
  const float* src = (m == 0) ? wq : (m == 1) ? wk : (m == 2) ? wv : op;
  int tx = threadIdx.x & 31, ty = threadIdx.x >> 5;
  int r0 = tr * 32, c0 = tc * 32;
#pragma unroll
  for (int j = 0; j < 4; ++j)
    tile[ty + j * 8][tx] = src[(size_t)(r0 + ty + j * 8) * 768 + c0 + tx];
  __syncthreads();
#pragma unroll
  for (int j = 0; j < 4; ++j) {
    float v = tile[tx][ty + j * 8];
    size_t o = (size_t)(c0 + ty + j * 8) * 768 + r0 + tx;
    if (m < 3) {
      size_t oo = (size_t)m * (768 * 768) + o;
      __bf16 h = (__bf16)v;
      wt_h[oo] = h;
      wt_l[oo] = (__bf16)(v - (float)h);
    } else {
      wot[o] = (_Float16)v;
    }
  }
}

// ---------------- QK GEMM: 3-term split-bf16, dbuf + swizzled LDS ----------------
// cols 0..1535 (Q then K). Outputs f16 (Q pre-scaled by QSCALE).
__global__ __launch_bounds__(256) void k_qk_gemm(
    const __bf16* __restrict__ Ah, const __bf16* __restrict__ Al,
    const __bf16* __restrict__ Bh, const __bf16* __restrict__ Bl,
    _Float16* __restrict__ qf_o, _Float16* __restrict__ kf_o) {
  __shared__ __align__(16) __bf16 AsH[2][128 * 32];
  __shared__ __align__(16) __bf16 AsL[2][128 * 32];
  __shared__ __align__(16) __bf16 BsH[2][128 * 32];
  __shared__ __align__(16) __bf16 BsL[2][128 * 32];
  int t = threadIdx.x, lane = t & 63, wid = t >> 6;
  int l15 = lane & 15, lh = lane >> 4;
  int bid = blockIdx.x;
  int mt = bid & 63, nt = bid >> 6;          // 64 x 12
  int m0 = mt * 128, n0 = nt * 128;
  int wr = wid >> 1, wc = wid & 1;
  f32x4 acc[4][4];
#pragma unroll
  for (int i = 0; i < 4; ++i)
#pragma unroll
    for (int j = 0; j < 4; ++j) acc[i][j] = (f32x4){0.f, 0.f, 0.f, 0.f};

  // staging: inverse-swizzled global source, linear LDS dest (rule #21)
  int row0 = t >> 2;
  int kkA = (((t & 3) ^ ((row0 >> 1) & 3)) << 3);   // swizzled 8-elem block
  char* lAH[2] = {(char*)AsH[0] + wid * 1024, (char*)AsH[1] + wid * 1024};
  char* lAL[2] = {(char*)AsL[0] + wid * 1024, (char*)AsL[1] + wid * 1024};
  char* lBH[2] = {(char*)BsH[0] + wid * 1024, (char*)BsH[1] + wid * 1024};
  char* lBL[2] = {(char*)BsL[0] + wid * 1024, (char*)BsL[1] + wid * 1024};

#define QK_STAGE(bb, k0s) do {                                               \
    size_t a0 = (size_t)(m0 + row0) * 768 + (k0s) + kkA;                     \
    size_t a1 = a0 + (size_t)64 * 768;                                       \
    size_t b0 = (size_t)(n0 + row0) * 768 + (k0s) + kkA;                     \
    size_t b1 = b0 + (size_t)64 * 768;                                       \
    GLL16(Ah + a0, lAH[bb]); GLL16(Ah + a1, lAH[bb] + 4096);                 \
    GLL16(Bh + b0, lBH[bb]); GLL16(Bh + b1, lBH[bb] + 4096);                 \
    GLL16(Al + a0, lAL[bb]); GLL16(Al + a1, lAL[bb] + 4096);                 \
    GLL16(Bl + b0, lBL[bb]); GLL16(Bl + b1, lBL[bb] + 4096);                 \
  } while (0)

  QK_STAGE(0, 0);
  asm volatile("s_waitcnt vmcnt(0)" ::: "memory");
  __syncthreads();

  for (int tt = 0; tt < 24; ++tt) {
    int cur = tt & 1;
    if (tt < 23) QK_STAGE(cur ^ 1, (tt + 1) * 32);

    bf16x8 af[4], alf[4], bf_[4], blf[4];
#pragma unroll
    for (int i = 0; i < 4; ++i) {
      int rowA = wr * 64 + i * 16 + l15;
      int aoff = rowA * 64 + (((lh ^ (rowA >> 1)) & 3) << 4);
      int rowB = wc * 64 + i * 16 + l15;
      int boff = rowB * 64 + (((lh ^ (rowB >> 1)) & 3) << 4);
      af[i]  = *(const bf16x8*)((char*)AsH[cur] + aoff);
      alf[i] = *(const bf16x8*)((char*)AsL[cur] + aoff);
      bf_[i] = *(const bf16x8*)((char*)BsH[cur] + boff);
      blf[i] = *(const bf16x8*)((char*)BsL[cur] + boff);
    }
    __builtin_amdgcn_s_setprio(1);
#pragma unroll
    for (int i = 0; i < 4; ++i)
#pragma unroll
      for (int j = 0; j < 4; ++j) {
        acc[i][j] = MFMA16(af[i], bf_[j], acc[i][j]);
        acc[i][j] = MFMA16(af[i], blf[j], acc[i][j]);
        acc[i][j] = MFMA16(alf[i], bf_[j], acc[i][j]);
      }
    __builtin_amdgcn_s_setprio(0);
    asm volatile("s_waitcnt vmcnt(0)" ::: "memory");
    __syncthreads();
  }
#undef QK_STAGE

#pragma unroll
  for (int j = 0; j < 4; ++j) {
    int c = n0 + wc * 64 + j * 16 + l15;
    int which = c / 768; int cc = c - which * 768;
    int hh = cc >> 6, d = cc & 63;
#pragma unroll
    for (int i = 0; i < 4; ++i)
#pragma unroll
      for (int r = 0; r < 4; ++r) {
        int m = m0 + wr * 64 + i * 16 + lh * 4 + r;
        int bb = m >> 11, n = m & 2047;
        float v = acc[i][j][r];
        size_t o = ((size_t)(bb * 12 + hh) * 2048 + n) * 64 + d;
        if (which == 0) qf_o[o] = (_Float16)(v * QSCALE);
        else            kf_o[o] = (_Float16)v;
      }
  }
}

// ---------------- V GEMM: 1-term bf16, dbuf + swizzled LDS ----------------
__global__ __launch_bounds__(256) void k_v_gemm(
    const __bf16* __restrict__ A, const __bf16* __restrict__ Bt,
    _Float16* __restrict__ vT_o) {
  __shared__ __align__(16) __bf16 As[2][128 * 32];
  __shared__ __align__(16) __bf16 Bs[2][128 * 32];
  int t = threadIdx.x, lane = t & 63, wid = t >> 6;
  int l15 = lane & 15, lh = lane >> 4;
  int bid = blockIdx.x;
  int mt = bid & 63, nt = bid >> 6;          // 64 x 6
  int m0 = mt * 128, n0 = 1536 + nt * 128;
  int wr = wid >> 1, wc = wid & 1;
  f32x4 acc[4][4];
#pragma unroll
  for (int i = 0; i < 4; ++i)
#pragma unroll
    for (int j = 0; j < 4; ++j) acc[i][j] = (f32x4){0.f, 0.f, 0.f, 0.f};
  int row0 = t >> 2;
  int kkA = (((t & 3) ^ ((row0 >> 1) & 3)) << 3);
  char* lA[2] = {(char*)As[0] + wid * 1024, (char*)As[1] + wid * 1024};
  char* lB[2] = {(char*)Bs[0] + wid * 1024, (char*)Bs[1] + wid * 1024};

#define V_STAGE(bb, k0s) do {                                                \
    size_t a0 = (size_t)(m0 + row0) * 768 + (k0s) + kkA;                     \
    size_t b0 = (size_t)(n0 + row0) * 768 + (k0s) + kkA;                     \
    GLL16(A + a0, lA[bb]);  GLL16(A + a0 + (size_t)64 * 768, lA[bb] + 4096); \
    GLL16(Bt + b0, lB[bb]); GLL16(Bt + b0 + (size_t)64 * 768, lB[bb] + 4096);\
  } while (0)

  V_STAGE(0, 0);
  asm volatile("s_waitcnt vmcnt(0)" ::: "memory");
  __syncthreads();

  for (int tt = 0; tt < 24; ++tt) {
    int cur = tt & 1;
    if (tt < 23) V_STAGE(cur ^ 1, (tt + 1) * 32);
    bf16x8 af[4], bf_[4];
#pragma unroll
    for (int i = 0; i < 4; ++i) {
      int rowA = wr * 64 + i * 16 + l15;
      int aoff = rowA * 64 + (((lh ^ (rowA >> 1)) & 3) << 4);
      int rowB = wc * 64 + i * 16 + l15;
      int boff = rowB * 64 + (((lh ^ (rowB >> 1)) & 3) << 4);
      af[i]  = *(const bf16x8*)((char*)As[cur] + aoff);
      bf_[i] = *(const bf16x8*)((char*)Bs[cur] + boff);
    }
    __builtin_amdgcn_s_setprio(1);
#pragma unroll
    for (int i = 0; i < 4; ++i)
#pragma unroll
      for (int j = 0; j < 4; ++j) acc[i][j] = MFMA16(af[i], bf_[j], acc[i][j]);
    __builtin_amdgcn_s_setprio(0);
    asm volatile("s_waitcnt vmcnt(0)" ::: "memory");
    __syncthreads();
  }
#undef V_STAGE

#pragma unroll
  for (int j = 0; j < 4; ++j) {
    int c = n0 + wc * 64 + j * 16 + l15;
    int cc = c - 1536;
    int hh = cc >> 6, d = cc & 63;
#pragma unroll
    for (int i = 0; i < 4; ++i)
#pragma unroll
      for (int r = 0; r < 4; ++r) {
        int m = m0 + wr * 64 + i * 16 + lh * 4 + r;
        int bb = m >> 11, n = m & 2047;
        vT_o[((size_t)(bb * 12 + hh) * 64 + d) * 2048 + n] = (_Float16)acc[i][j][r];
      }
  }
}

// ---------------- causal flash attention (f16, dbuf, defer-max) ----------------
__global__ __launch_bounds__(256) void k_attn(
    const _Float16* __restrict__ Qf, const _Float16* __restrict__ Kf,
    const _Float16* __restrict__ Vt, _Float16* __restrict__ ctx) {
  __shared__ __align__(16) _Float16 Ks[2][64 * 64];
  __shared__ __align__(16) _Float16 Vs[2][64 * 64];
  __shared__ __align__(16) _Float16 Pt[4][32 * 64];
  int t = threadIdx.x, lane = t & 63, wid = t >> 6;
  int l15 = lane & 15, lh = lane >> 4;
  int bid = blockIdx.x;
  int bh = bid % 48;
  int qt = 15 - bid / 48;                    // heavy tiles dispatch first
  int qbase = qt * 128 + wid * 32;
  size_t base = (size_t)bh * (2048 * 64);
  char* ptw = (char*)Pt[wid];

  int skey = t >> 3, sdb = t & 7;
  int ssw = (sdb ^ (skey & 7)) * 8;
  const _Float16* ksrc = Kf + base + (size_t)skey * 64 + ssw;
  const _Float16* vsrc = Vt + base + (size_t)skey * 2048 + ssw;
  char* dK[2] = {(char*)Ks[0] + wid * 1024, (char*)Ks[1] + wid * 1024};
  char* dV[2] = {(char*)Vs[0] + wid * 1024, (char*)Vs[1] + wid * 1024};

#define ATT_STAGE(bb, k0s) do {                                    \
    GLL16(ksrc + (size_t)(k0s) * 64, dK[bb]);                      \
    GLL16(ksrc + (size_t)(k0s) * 64 + 2048, dK[bb] + 4096);        \
    GLL16(vsrc + (k0s), dV[bb]);                                   \
    GLL16(vsrc + (k0s) + 32 * 2048, dV[bb] + 4096);                \
  } while (0)

  f16x8 qf[2][2];
#pragma unroll
  for (int i = 0; i < 2; ++i)
#pragma unroll
    for (int kk = 0; kk < 2; ++kk)
      qf[i][kk] = *(const f16x8*)(Qf + base +
          (size_t)(qbase + i * 16 + l15) * 64 + kk * 32 + lh * 8);

  f32x4 o[2][4];
#pragma unroll
  for (int i = 0; i < 2; ++i)
#pragma unroll
    for (int d = 0; d < 4; ++d) o[i][d] = (f32x4){0.f, 0.f, 0.f, 0.f};
  float mrun[2] = {-1e30f, -1e30f}, lrun[2] = {0.f, 0.f};

  int nIter = 2 * qt + 2;
  ATT_STAGE(0, 0);
  asm volatile("s_waitcnt vmcnt(0)" ::: "memory");
  __syncthreads();

  for (int it = 0; it < nIter; ++it) {
    int cur = it & 1;
    int k0 = it * 64;
    if (it + 1 < nIter) ATT_STAGE(cur ^ 1, k0 + 64);

    if (k0 <= qbase + 31) {
      f32x4 s[4][2];
#pragma unroll
      for (int j = 0; j < 4; ++j)
#pragma unroll
        for (int i = 0; i < 2; ++i) s[j][i] = (f32x4){0.f, 0.f, 0.f, 0.f};
      __builtin_amdgcn_s_setprio(1);
#pragma unroll
      for (int j = 0; j < 4; ++j) {
        int kr = j * 16 + l15;
#pragma unroll
        for (int kk = 0; kk < 2; ++kk) {
          int sw = ((kk * 4 + lh) ^ (kr & 7)) << 4;
          f16x8 kf = *(const f16x8*)((char*)Ks[cur] + kr * 128 + sw);
          s[j][0] = MFMAF16(kf, qf[0][kk], s[j][0]);
          s[j][1] = MFMAF16(kf, qf[1][kk], s[j][1]);
        }
      }
      __builtin_amdgcn_s_setprio(0);

      if (k0 + 63 > qbase) {                 // diagonal: causal mask
#pragma unroll
        for (int j = 0; j < 4; ++j)
#pragma unroll
          for (int i = 0; i < 2; ++i)
#pragma unroll
            for (int r = 0; r < 4; ++r) {
              int key = k0 + j * 16 + lh * 4 + r;
              int qg = qbase + i * 16 + l15;
              if (key > qg) s[j][i][r] = -1e30f;
            }
      }

      // --- online softmax with defer-max (T13, THR=8 exp2-units) ---
#pragma unroll
      for (int i = 0; i < 2; ++i) {
        float m01 = fmaxf(fmaxf(s[0][i][0], s[0][i][1]), fmaxf(s[0][i][2], s[0][i][3]));
        float m23 = fmaxf(fmaxf(s[1][i][0], s[1][i][1]), fmaxf(s[1][i][2], s[1][i][3]));
        float m45 = fmaxf(fmaxf(s[2][i][0], s[2][i][1]), fmaxf(s[2][i][2], s[2][i][3]));
        float m67 = fmaxf(fmaxf(s[3][i][0], s[3][i][1]), fmaxf(s[3][i][2], s[3][i][3]));
        float mx = fmaxf(fmaxf(m01, m23), fmaxf(m45, m67));
        mx = fmaxf(mx, __shfl_xor(mx, 16));
        mx = fmaxf(mx, __shfl_xor(mx, 32));
        bool keep = !__all(mx <= mrun[i] + 8.f);
        float mn = mrun[i];
        if (keep) {
          mn = fmaxf(mrun[i], mx);
          float alpha = fexp2(mrun[i] - mn);
          mrun[i] = mn;
          lrun[i] *= alpha;
#pragma unroll
          for (int d = 0; d < 4; ++d) o[i][d] *= alpha;
        }
        float rsum = 0.f;
#pragma unroll
        for (int j = 0; j < 4; ++j)
#pragma unroll
          for (int r = 0; r < 4; ++r) {
            float e = fexp2(s[j][i][r] - mn);
            s[j][i][r] = e;
            rsum += e;
          }
        rsum += __shfl_xor(rsum, 16);
        rsum += __shfl_xor(rsum, 32);
        lrun[i] += rsum;
#pragma unroll
        for (int j = 0; j < 4; ++j) {
          f16x4 pk = { (_Float16)s[j][i][0], (_Float16)s[j][i][1],
                       (_Float16)s[j][i][2], (_Float16)s[j][i][3] };
          int row = 16 * i + l15;
          int boff = (row * 128 + j * 32 + lh * 8) ^ ((l15 & 7) << 4);
          *(f16x4*)(ptw + boff) = pk;
        }
      }
      asm volatile("" ::: "memory");
      f16x8 pa[2][2];
#pragma unroll
      for (int i = 0; i < 2; ++i)
#pragma unroll
        for (int kk = 0; kk < 2; ++kk) {
          int row = 16 * i + l15;
          int boff = (row * 128 + kk * 64 + lh * 16) ^ ((l15 & 7) << 4);
          pa[i][kk] = *(const f16x8*)(ptw + boff);
        }
      asm volatile("" ::: "memory");

      __builtin_amdgcn_s_setprio(1);
#pragma unroll
      for (int dt = 0; dt < 4; ++dt) {
        int dr = dt * 16 + l15;
#pragma unroll
        for (int kk = 0; kk < 2; ++kk) {
          int sw = ((kk * 4 + lh) ^ (dr & 7)) << 4;
          f16x8 vf = *(const f16x8*)((char*)Vs[cur] + dr * 128 + sw);
          o[0][dt] = MFMAF16(vf, pa[0][kk], o[0][dt]);
          o[1][dt] = MFMAF16(vf, pa[1][kk], o[1][dt]);
        }
      }
      __builtin_amdgcn_s_setprio(0);
    }
    asm volatile("s_waitcnt vmcnt(0)" ::: "memory");
    __syncthreads();
  }
#undef ATT_STAGE

  int b = bh / 12, hh = bh - (bh / 12) * 12;
  float inv[2] = {1.f / lrun[0], 1.f / lrun[1]};
#pragma unroll
  for (int i = 0; i < 2; ++i)
#pragma unroll
    for (int dt = 0; dt < 4; ++dt) {
      f16x4 cw = { (_Float16)(o[i][dt][0] * inv[i]), (_Float16)(o[i][dt][1] * inv[i]),
                   (_Float16)(o[i][dt][2] * inv[i]), (_Float16)(o[i][dt][3] * inv[i]) };
      int row = 16 * i + l15;
      int boff = (row * 128 + dt * 32 + lh * 8) ^ ((l15 & 7) << 4);
      *(f16x4*)(ptw + boff) = cw;
    }
  asm volatile("" ::: "memory");
  int lr = lane >> 1, hc = lane & 1;
#pragma unroll
  for (int q16 = 0; q16 < 4; ++q16) {
    int boff = (lr * 128 + hc * 64 + q16 * 16) ^ ((lr & 7) << 4);
    f16x8 vv = *(const f16x8*)(ptw + boff);
    *(f16x8*)(ctx + ((size_t)b * 2048 + qbase + lr) * 768 + hh * 64 + hc * 32 + q16 * 8) = vv;
  }
}

// ------------- out projection: f16 in, fp32 out, dbuf + swizzled LDS -------------
__global__ __launch_bounds__(256) void k_out_gemm(const _Float16* __restrict__ A,
                                                  const _Float16* __restrict__ Bt,
                                                  float* __restrict__ C) {
  __shared__ __align__(16) _Float16 As[2][128 * 32];
  __shared__ __align__(16) _Float16 Bs[2][128 * 32];
  int t = threadIdx.x, lane = t & 63, wid = t >> 6;
  int l15 = lane & 15, lh = lane >> 4;
  int bid = blockIdx.x;
  int mt = bid & 63, nt = bid >> 6;
  int m0 = mt * 128, n0 = nt * 128;
  int wr = wid >> 1, wc = wid & 1;
  f32x4 acc[4][4];
#pragma unroll
  for (int i = 0; i < 4; ++i)
#pragma unroll
    for (int j = 0; j < 4; ++j) acc[i][j] = (f32x4){0.f, 0.f, 0.f, 0.f};
  int row0 = t >> 2;
  int kkA = (((t & 3) ^ ((row0 >> 1) & 3)) << 3);
  char* lA[2] = {(char*)As[0] + wid * 1024, (char*)As[1] + wid * 1024};
  char* lB[2] = {(char*)Bs[0] + wid * 1024, (char*)Bs[1] + wid * 1024};

#define OUT_STAGE(bb, k0s) do {                                              \
    size_t a0 = (size_t)(m0 + row0) * 768 + (k0s) + kkA;                     \
    size_t b0 = (size_t)(n0 + row0) * 768 + (k0s) + kkA;                     \
    GLL16(A + a0, lA[bb]);  GLL16(A + a0 + (size_t)64 * 768, lA[bb] + 4096); \
    GLL16(Bt + b0, lB[bb]); GLL16(Bt + b0 + (size_t)64 * 768, lB[bb] + 4096);\
  } while (0)

  OUT_STAGE(0, 0);
  asm volatile("s_waitcnt vmcnt(0)" ::: "memory");
  __syncthreads();

  for (int tt = 0; tt < 24; ++tt) {
    int cur = tt & 1;
    if (tt < 23) OUT_STAGE(cur ^ 1, (tt + 1) * 32);
    f16x8 af[4], bf_[4];
#pragma unroll
    for (int i = 0; i < 4; ++i) {
      int rowA = wr * 64 + i * 16 + l15;
      int aoff = rowA * 64 + (((lh ^ (rowA >> 1)) & 3) << 4);
      int rowB = wc * 64 + i * 16 + l15;
      int boff = rowB * 64 + (((lh ^ (rowB >> 1)) & 3) << 4);
      af[i]  = *(const f16x8*)((char*)As[cur] + aoff);
      bf_[i] = *(const f16x8*)((char*)Bs[cur] + boff);
    }
    __builtin_amdgcn_s_setprio(1);
#pragma unroll
    for (int i = 0; i < 4; ++i)
#pragma unroll
      for (int j = 0; j < 4; ++j) acc[i][j] = MFMAF16(af[i], bf_[j], acc[i][j]);
    __builtin_amdgcn_s_setprio(0);
    asm volatile("s_waitcnt vmcnt(0)" ::: "memory");
    __syncthreads();
  }
#undef OUT_STAGE

#pragma unroll
  for (int j = 0; j < 4; ++j) {
    int c = n0 + wc * 64 + j * 16 + l15;
#pragma unroll
    for (int i = 0; i < 4; ++i)
#pragma unroll
      for (int r = 0; r < 4; ++r) {
        int m = m0 + wr * 64 + i * 16 + lh * 4 + r;
        C[(size_t)m * 768 + c] = acc[i][j][r];
      }
  }
}

extern "C" void kernel_launch(void* const* d_in, const int* in_sizes, int n_in,
                              void* d_out, int out_size, void* d_ws, size_t ws_size,
                              hipStream_t stream) {
  const float* x  = (const float*)d_in[0];
  const float* wq = (const float*)d_in[1];
  const float* wk = (const float*)d_in[2];
  const float* wv = (const float*)d_in[3];
  const float* op = (const float*)d_in[4];
  float* out = (float*)d_out;

  char* ws = (char*)d_ws;
  const size_t SZ = (size_t)8192 * 768 * 2;
  __bf16* xh     = (__bf16*)ws;    ws += SZ;
  __bf16* xl     = (__bf16*)ws;    ws += SZ;
  __bf16* wt_h   = (__bf16*)ws;    ws += (size_t)2304 * 768 * 2;
  __bf16* wt_l   = (__bf16*)ws;    ws += (size_t)2304 * 768 * 2;
  _Float16* wot  = (_Float16*)ws;  ws += (size_t)768 * 768 * 2;
  _Float16* qf   = (_Float16*)ws;  ws += SZ;
  _Float16* kf   = (_Float16*)ws;  ws += SZ;
  _Float16* vT   = (_Float16*)ws;  ws += SZ;
  _Float16* ctx  = (_Float16*)ws;  ws += SZ;

  hipLaunchKernelGGL(k_conv, dim3(3072 + 2304), dim3(256), 0, stream,
                     x, wq, wk, wv, op, xh, xl, wt_h, wt_l, wot);
  hipLaunchKernelGGL(k_qk_gemm, dim3(64 * 12), dim3(256), 0, stream,
                     xh, xl, wt_h, wt_l, qf, kf);
  hipLaunchKernelGGL(k_v_gemm, dim3(64 * 6), dim3(256), 0, stream, xh, wt_h, vT);
  hipLaunchKernelGGL(k_attn, dim3(48 * 16), dim3(256), 0, stream, qf, kf, vT, ctx);
  hipLaunchKernelGGL(k_out_gemm, dim3(64 * 6), dim3(256), 0, stream, ctx, wot, out);
}